// Round 2
// 938.708 us; speedup vs baseline: 1.0535x; 1.0535x over previous
//
#include <hip/hip_runtime.h>

#define LN_EPS 1e-5f
#define RSCALE (1.0f / 30.0f)

typedef short short8  __attribute__((ext_vector_type(8)));
typedef short short4v __attribute__((ext_vector_type(4)));
typedef float f32x4   __attribute__((ext_vector_type(4)));

__device__ __forceinline__ unsigned short f2bf(float f) {
    unsigned u = __builtin_bit_cast(unsigned, f);
    u = u + 0x7FFFu + ((u >> 16) & 1u);   // round-to-nearest-even
    return (unsigned short)(u >> 16);
}

__device__ __forceinline__ float gelu_f(float x) {
    // tanh-form gelu; |err| vs exact erf-gelu ~3e-3, scaled by alpha=0.01 downstream
    float u  = 0.7978845608028654f * (x + 0.044715f * x * x * x);
    float e  = __expf(-2.0f * fabsf(u));
    float t  = 1.0f - 2.0f * e / (1.0f + e);
    return 0.5f * x * (1.0f + copysignf(t, u));
}

__device__ __forceinline__ f32x4 zero4() {
    f32x4 v; v.x = 0.f; v.y = 0.f; v.z = 0.f; v.w = 0.f; return v;
}

// ---------------------------------------------------------------------------
// Kernel 0: bf16-transpose weights.
//   w1bt: [128 m][384 k]  = W1[128+k][m]   (h_E half of W1 only)
//   w2t/w3t: [128 m][128 k]
// ---------------------------------------------------------------------------
__global__ __launch_bounds__(256) void prep_w(
    const float* __restrict__ W1, const float* __restrict__ W2,
    const float* __restrict__ W3,
    unsigned short* __restrict__ w1bt, unsigned short* __restrict__ w2t,
    unsigned short* __restrict__ w3t)
{
    int t = blockIdx.x * 256 + threadIdx.x;
    if (t < 49152) {                       // W1 rows 128..511 -> w1bt [128][384]
        int m = t & 127, kk = t >> 7;
        w1bt[m * 384 + kk] = f2bf(W1[(kk + 128) * 128 + m]);
    } else if (t < 65536) {                // W2: [128][128] -> w2t [128][128]
        int u = t - 49152, m = u & 127, k = u >> 7;
        w2t[m * 128 + k] = f2bf(W2[k * 128 + m]);
    } else if (t < 81920) {                // W3
        int u = t - 65536, m = u & 127, k = u >> 7;
        w3t[m * 128 + k] = f2bf(W3[k * 128 + m]);
    }
}

// ---------------------------------------------------------------------------
// Kernel 1: fused edge MLP + masked K-reduce -> dh
// 2 nodes/WG (96 edge rows), 4 waves. Wave w: node g=w&1, neuron half mh=w>>1.
// h_V@W1a+b1 is identical across the 48 neighbors of a node -> hoisted to a
// once-per-node fp32 prologue and used as the MFMA accumulator init, so
// GEMM1 is 6 K-chunks of h_E only (was 8).  Single Hb buffer (GEMM2 fully
// consumes it before epilogue-2 rewrites in place) -> 52.4 KB LDS -> 3 wg/CU.
// Staging = proven round-0 template: VGPR loads -> ds_write, one barrier pair
// per chunk (race-screened structure; latency hidden by 12 waves/CU TLP).
// LDS XOR swizzle both sides: addr = row*ROWB + 16*(kb ^ (row&7)).
// ---------------------------------------------------------------------------
__global__ __launch_bounds__(256, 3) void edge_mlp(
    const float* __restrict__ hV, const float* __restrict__ hE,
    const float* __restrict__ mAtt,
    const float* __restrict__ W1, const float* __restrict__ b1,
    const unsigned short* __restrict__ w1bt, const unsigned short* __restrict__ w2t,
    const unsigned short* __restrict__ w3t,
    const float* __restrict__ b2, const float* __restrict__ b3,
    float* __restrict__ dh)
{
    __shared__ __align__(16) short A1[96 * 64];    // edge-feature chunk [96][64]
    __shared__ __align__(16) short Wb[128 * 64];   // weight chunk [128][64]
    __shared__ __align__(16) short Hb[96 * 128];   // hidden activations (in-place reuse)
    __shared__ float mb[96];                       // mask_attend rows

    const int tid  = threadIdx.x;
    const int lane = tid & 63;
    const int wv   = tid >> 6;
    const int g    = wv & 1;
    const int mh   = wv >> 1;
    const int ln   = lane & 15;
    const int kg   = lane >> 4;
    const int node0 = blockIdx.x * 2;

    const int srow = tid >> 4;             // staging row 0..15
    const int c4   = (tid & 15) * 4;       // staging col (4 floats)
    const int kb_w = c4 >> 3;              // 16B sub-block 0..7
    const int c4lo = c4 & 4;               // 0|4 shorts within sub-block

    if (tid < 96) mb[tid] = mAtt[node0 * 48 + tid];

    // ---- prologue: nodeV1[g][m] = b1[m] + sum_k hV[n][k] * W1[k][m] (fp32) ----
    float* nv = (float*)A1;                // 256 floats, overlays A1 (dead until GEMM1)
    {
        const int gg = tid >> 7, m = tid & 127;
        const float* hv = hV + (node0 + gg) * 128;
        const float* wc = W1 + m;
        float a0 = 0.f, a1 = 0.f, a2 = 0.f, a3 = 0.f;
        for (int k = 0; k < 128; k += 4) {
            const float4 h4 = *(const float4*)(hv + k);
            a0 += h4.x * wc[(k + 0) * 128];
            a1 += h4.y * wc[(k + 1) * 128];
            a2 += h4.z * wc[(k + 2) * 128];
            a3 += h4.w * wc[(k + 3) * 128];
        }
        nv[tid] = b1[m] + (a0 + a1) + (a2 + a3);
    }
    __syncthreads();

    // ---- acc init from nodeV1 (same value for every edge row of the node) ----
    f32x4 acc[4][3];
#pragma unroll
    for (int j = 0; j < 4; ++j) {
        const float4 iv = *(const float4*)&nv[g * 128 + (4 * mh + j) * 16 + kg * 4];
#pragma unroll
        for (int i = 0; i < 3; ++i) {
            acc[j][i].x = iv.x; acc[j][i].y = iv.y;
            acc[j][i].z = iv.z; acc[j][i].w = iv.w;
        }
    }
    __syncthreads();                       // nv reads done; A1 free for staging

    // -------- GEMM1: hE[96x384] @ W1b, 6 K-chunks of 64 --------
    for (int c = 0; c < 6; ++c) {
        const int kc = c * 64;
        // stage A chunk (fp32 -> bf16)
#pragma unroll
        for (int rep = 0; rep < 6; ++rep) {
            const int r = rep * 16 + srow;
            const float4 v = *(const float4*)(hE + (node0 * 48 + r) * 384 + kc + c4);
            short4v p;
            p.x = (short)f2bf(v.x); p.y = (short)f2bf(v.y);
            p.z = (short)f2bf(v.z); p.w = (short)f2bf(v.w);
            *(short4v*)&A1[r * 64 + ((kb_w ^ (r & 7)) * 8) + c4lo] = p;
        }
        // stage W1T chunk (already bf16)
#pragma unroll
        for (int rep = 0; rep < 4; ++rep) {
            const int u = rep * 256 + tid;
            const int m = u >> 3, kb = u & 7;
            short8 val = *(const short8*)(w1bt + m * 384 + kc + kb * 8);
            *(short8*)&Wb[m * 64 + ((kb ^ (m & 7)) * 8)] = val;
        }
        __syncthreads();
#pragma unroll
        for (int s = 0; s < 2; ++s) {
            const int kb = s * 4 + kg;
            short8 bf[3], af[4];
#pragma unroll
            for (int i = 0; i < 3; ++i) {
                const int r = (3 * g + i) * 16 + ln;
                bf[i] = *(const short8*)&A1[r * 64 + ((kb ^ (r & 7)) * 8)];
            }
#pragma unroll
            for (int j = 0; j < 4; ++j) {
                const int m = (4 * mh + j) * 16 + ln;
                af[j] = *(const short8*)&Wb[m * 64 + ((kb ^ (m & 7)) * 8)];
            }
#pragma unroll
            for (int j = 0; j < 4; ++j)
#pragma unroll
                for (int i = 0; i < 3; ++i)
                    acc[j][i] = __builtin_amdgcn_mfma_f32_16x16x32_bf16(af[j], bf[i], acc[j][i], 0, 0, 0);
        }
        __syncthreads();
    }

    // epilogue 1: gelu(x) -> Hb   (b1 already folded into nodeV1 init)
#pragma unroll
    for (int j = 0; j < 4; ++j) {
        const int m0 = (4 * mh + j) * 16 + kg * 4;
#pragma unroll
        for (int i = 0; i < 3; ++i) {
            const int r = (3 * g + i) * 16 + ln;
            short4v p;
            p.x = (short)f2bf(gelu_f(acc[j][i].x));
            p.y = (short)f2bf(gelu_f(acc[j][i].y));
            p.z = (short)f2bf(gelu_f(acc[j][i].z));
            p.w = (short)f2bf(gelu_f(acc[j][i].w));
            *(short4v*)&Hb[r * 128 + (((m0 >> 3) ^ (r & 7)) * 8) + (m0 & 4)] = p;
        }
    }

    // -------- GEMM2 (Hb @ W2 -> Hb, in place) and GEMM3 (Hb @ W3 -> reduce) ----
    for (int L = 0; L < 2; ++L) {
#pragma unroll
        for (int j = 0; j < 4; ++j)
#pragma unroll
            for (int i = 0; i < 3; ++i) acc[j][i] = zero4();

        const unsigned short* wt = (L == 0) ? w2t : w3t;
        for (int c = 0; c < 2; ++c) {
            const int kc = c * 64;
#pragma unroll
            for (int rep = 0; rep < 4; ++rep) {
                const int u = rep * 256 + tid;
                const int m = u >> 3, kb = u & 7;
                short8 val = *(const short8*)(wt + m * 128 + kc + kb * 8);
                *(short8*)&Wb[m * 64 + ((kb ^ (m & 7)) * 8)] = val;
            }
            __syncthreads();
#pragma unroll
            for (int s = 0; s < 2; ++s) {
                const int kbW = s * 4 + kg;
                const int kbH = c * 8 + s * 4 + kg;
                short8 bf[3], af[4];
#pragma unroll
                for (int i = 0; i < 3; ++i) {
                    const int r = (3 * g + i) * 16 + ln;
                    bf[i] = *(const short8*)&Hb[r * 128 + ((kbH ^ (r & 7)) * 8)];
                }
#pragma unroll
                for (int j = 0; j < 4; ++j) {
                    const int m = (4 * mh + j) * 16 + ln;
                    af[j] = *(const short8*)&Wb[m * 64 + ((kbW ^ (m & 7)) * 8)];
                }
#pragma unroll
                for (int j = 0; j < 4; ++j)
#pragma unroll
                    for (int i = 0; i < 3; ++i)
                        acc[j][i] = __builtin_amdgcn_mfma_f32_16x16x32_bf16(af[j], bf[i], acc[j][i], 0, 0, 0);
            }
            __syncthreads();
        }

        if (L == 0) {
            // epilogue 2: gelu(x + b2) -> Hb (all reads of old Hb completed above)
#pragma unroll
            for (int j = 0; j < 4; ++j) {
                const int m0 = (4 * mh + j) * 16 + kg * 4;
                const float4 bb = *(const float4*)(b2 + m0);
#pragma unroll
                for (int i = 0; i < 3; ++i) {
                    const int r = (3 * g + i) * 16 + ln;
                    short4v p;
                    p.x = (short)f2bf(gelu_f(acc[j][i].x + bb.x));
                    p.y = (short)f2bf(gelu_f(acc[j][i].y + bb.y));
                    p.z = (short)f2bf(gelu_f(acc[j][i].z + bb.z));
                    p.w = (short)f2bf(gelu_f(acc[j][i].w + bb.w));
                    *(short4v*)&Hb[r * 128 + (((m0 >> 3) ^ (r & 7)) * 8) + (m0 & 4)] = p;
                }
            }
        } else {
            // epilogue 3: dh[node][m] = (1/30) * sum_rows mask*(x + b3)
#pragma unroll
            for (int j = 0; j < 4; ++j) {
                const int m0 = (4 * mh + j) * 16 + kg * 4;
                const float4 bb = *(const float4*)(b3 + m0);
                float s0 = 0.f, s1 = 0.f, s2 = 0.f, s3 = 0.f;
#pragma unroll
                for (int i = 0; i < 3; ++i) {
                    const int r = (3 * g + i) * 16 + ln;
                    const float mk = mb[r];
                    s0 += (acc[j][i].x + bb.x) * mk;
                    s1 += (acc[j][i].y + bb.y) * mk;
                    s2 += (acc[j][i].z + bb.z) * mk;
                    s3 += (acc[j][i].w + bb.w) * mk;
                }
#pragma unroll
                for (int off = 1; off < 16; off <<= 1) {
                    s0 += __shfl_xor(s0, off, 64);
                    s1 += __shfl_xor(s1, off, 64);
                    s2 += __shfl_xor(s2, off, 64);
                    s3 += __shfl_xor(s3, off, 64);
                }
                if (ln == 0) {
                    float4 o;
                    o.x = s0 * RSCALE; o.y = s1 * RSCALE;
                    o.z = s2 * RSCALE; o.w = s3 * RSCALE;
                    *(float4*)&dh[(node0 + g) * 128 + m0] = o;
                }
            }
        }
    }
}

// ---------------------------------------------------------------------------
// Kernel 2: per-node rezero+LN1 -> FFN(128->512->128) -> rezero+LN2 -> mask
// 16 nodes per WG, 512 WGs, fp32 VALU.
// ---------------------------------------------------------------------------
__global__ __launch_bounds__(256, 2) void node_ffn(
    const float* __restrict__ hV, const float* __restrict__ dh,
    const float* __restrict__ maskV,
    const float* __restrict__ g1, const float* __restrict__ be1,
    const float* __restrict__ g2, const float* __restrict__ be2,
    const float* __restrict__ Wi, const float* __restrict__ bi,
    const float* __restrict__ Wo, const float* __restrict__ bo,
    const float* __restrict__ alphap, float* __restrict__ out)
{
    __shared__ float hbuf[16 * 132];   // post-LN1 h
    __shared__ float hidb[16 * 516];   // hidden (512) per node
    __shared__ float obuf[16 * 132];   // FFN output

    const int tid = threadIdx.x;
    const float al = alphap[0];
    const int nb = blockIdx.x * 16;

    // ---- phase 1: x = hV + al*dh; LN1 -> hbuf ----
    {
        const int m = tid >> 4, s = tid & 15;
        const int i0 = s * 8;
        const int base = (nb + m) * 128 + i0;
        float x[8];
        {
            float4 a0 = *(const float4*)(dh + base);
            float4 a1 = *(const float4*)(dh + base + 4);
            float4 v0 = *(const float4*)(hV + base);
            float4 v1 = *(const float4*)(hV + base + 4);
            x[0] = v0.x + al * a0.x; x[1] = v0.y + al * a0.y;
            x[2] = v0.z + al * a0.z; x[3] = v0.w + al * a0.w;
            x[4] = v1.x + al * a1.x; x[5] = v1.y + al * a1.y;
            x[6] = v1.z + al * a1.z; x[7] = v1.w + al * a1.w;
        }
        float sm = 0.f;
#pragma unroll
        for (int q = 0; q < 8; ++q) sm += x[q];
#pragma unroll
        for (int off = 1; off < 16; off <<= 1) sm += __shfl_xor(sm, off, 64);
        const float mu = sm * (1.0f / 128.0f);
        float vs = 0.f;
#pragma unroll
        for (int q = 0; q < 8; ++q) { float d = x[q] - mu; vs += d * d; }
#pragma unroll
        for (int off = 1; off < 16; off <<= 1) vs += __shfl_xor(vs, off, 64);
        const float rs = rsqrtf(vs * (1.0f / 128.0f) + LN_EPS);
#pragma unroll
        for (int q = 0; q < 8; ++q)
            hbuf[m * 132 + i0 + q] = (x[q] - mu) * rs * g1[i0 + q] + be1[i0 + q];
    }
    __syncthreads();

    // ---- phase 2: hid = gelu(h @ Wi + bi) ----
    {
        const int jg = tid & 127, mhh = tid >> 7;
        const int j4 = jg * 4;
        float acc[8][4];
#pragma unroll
        for (int mm = 0; mm < 8; ++mm)
#pragma unroll
            for (int jj = 0; jj < 4; ++jj) acc[mm][jj] = 0.f;
        for (int i0 = 0; i0 < 128; i0 += 4) {
            float4 w0 = *(const float4*)(Wi + (i0 + 0) * 512 + j4);
            float4 w1 = *(const float4*)(Wi + (i0 + 1) * 512 + j4);
            float4 w2 = *(const float4*)(Wi + (i0 + 2) * 512 + j4);
            float4 w3 = *(const float4*)(Wi + (i0 + 3) * 512 + j4);
#pragma unroll
            for (int mm = 0; mm < 8; ++mm) {
                float4 h4 = *(const float4*)&hbuf[(mhh * 8 + mm) * 132 + i0];
                acc[mm][0] += h4.x * w0.x + h4.y * w1.x + h4.z * w2.x + h4.w * w3.x;
                acc[mm][1] += h4.x * w0.y + h4.y * w1.y + h4.z * w2.y + h4.w * w3.y;
                acc[mm][2] += h4.x * w0.z + h4.y * w1.z + h4.z * w2.z + h4.w * w3.z;
                acc[mm][3] += h4.x * w0.w + h4.y * w1.w + h4.z * w2.w + h4.w * w3.w;
            }
        }
        float4 bb = *(const float4*)(bi + j4);
#pragma unroll
        for (int mm = 0; mm < 8; ++mm) {
            float4 o;
            o.x = gelu_f(acc[mm][0] + bb.x);
            o.y = gelu_f(acc[mm][1] + bb.y);
            o.z = gelu_f(acc[mm][2] + bb.z);
            o.w = gelu_f(acc[mm][3] + bb.w);
            *(float4*)&hidb[(mhh * 8 + mm) * 516 + j4] = o;
        }
    }
    __syncthreads();

    // ---- phase 3: o = hid @ Wo + bo -> obuf ----
    {
        const int m = tid >> 4;
        const int n8 = (tid & 15) * 8;
        float4 r0, r1;
        r0.x = r0.y = r0.z = r0.w = 0.f;
        r1.x = r1.y = r1.z = r1.w = 0.f;
        for (int j0 = 0; j0 < 512; j0 += 4) {
            float4 hh = *(const float4*)&hidb[m * 516 + j0];
            float hq[4] = {hh.x, hh.y, hh.z, hh.w};
#pragma unroll
            for (int jj = 0; jj < 4; ++jj) {
                float4 w0 = *(const float4*)(Wo + (j0 + jj) * 128 + n8);
                float4 w1 = *(const float4*)(Wo + (j0 + jj) * 128 + n8 + 4);
                r0.x += hq[jj] * w0.x; r0.y += hq[jj] * w0.y;
                r0.z += hq[jj] * w0.z; r0.w += hq[jj] * w0.w;
                r1.x += hq[jj] * w1.x; r1.y += hq[jj] * w1.y;
                r1.z += hq[jj] * w1.z; r1.w += hq[jj] * w1.w;
            }
        }
        float4 q0 = *(const float4*)(bo + n8);
        float4 q1 = *(const float4*)(bo + n8 + 4);
        r0.x += q0.x; r0.y += q0.y; r0.z += q0.z; r0.w += q0.w;
        r1.x += q1.x; r1.y += q1.y; r1.z += q1.z; r1.w += q1.w;
        *(float4*)&obuf[m * 132 + n8]     = r0;
        *(float4*)&obuf[m * 132 + n8 + 4] = r1;
    }
    __syncthreads();

    // ---- phase 4: x = h + al*o; LN2; mask; store ----
    {
        const int m = tid >> 4, s = tid & 15;
        const int i0 = s * 8;
        float x[8];
#pragma unroll
        for (int q = 0; q < 8; ++q)
            x[q] = hbuf[m * 132 + i0 + q] + al * obuf[m * 132 + i0 + q];
        float sm = 0.f;
#pragma unroll
        for (int q = 0; q < 8; ++q) sm += x[q];
#pragma unroll
        for (int off = 1; off < 16; off <<= 1) sm += __shfl_xor(sm, off, 64);
        const float mu = sm * (1.0f / 128.0f);
        float vs = 0.f;
#pragma unroll
        for (int q = 0; q < 8; ++q) { float d = x[q] - mu; vs += d * d; }
#pragma unroll
        for (int off = 1; off < 16; off <<= 1) vs += __shfl_xor(vs, off, 64);
        const float rs = rsqrtf(vs * (1.0f / 128.0f) + LN_EPS);
        const float mk = maskV[nb + m];
        float y[8];
#pragma unroll
        for (int q = 0; q < 8; ++q)
            y[q] = ((x[q] - mu) * rs * g2[i0 + q] + be2[i0 + q]) * mk;
        float4 o0, o1;
        o0.x = y[0]; o0.y = y[1]; o0.z = y[2]; o0.w = y[3];
        o1.x = y[4]; o1.y = y[5]; o1.z = y[6]; o1.w = y[7];
        const int base = (nb + m) * 128 + i0;
        *(float4*)(out + base)     = o0;
        *(float4*)(out + base + 4) = o1;
    }
}

// ---------------------------------------------------------------------------
extern "C" void kernel_launch(void* const* d_in, const int* in_sizes, int n_in,
                              void* d_out, int out_size, void* d_ws, size_t ws_size,
                              hipStream_t stream)
{
    const float* hV  = (const float*)d_in[0];
    const float* hE  = (const float*)d_in[1];
    const float* mV  = (const float*)d_in[2];
    const float* mA  = (const float*)d_in[3];
    const float* W1  = (const float*)d_in[4];
    const float* b1  = (const float*)d_in[5];
    const float* W2  = (const float*)d_in[6];
    const float* b2  = (const float*)d_in[7];
    const float* W3  = (const float*)d_in[8];
    const float* b3  = (const float*)d_in[9];
    const float* g1  = (const float*)d_in[10];
    const float* be1 = (const float*)d_in[11];
    const float* g2  = (const float*)d_in[12];
    const float* be2 = (const float*)d_in[13];
    const float* Wi  = (const float*)d_in[14];
    const float* bi  = (const float*)d_in[15];
    const float* Wo  = (const float*)d_in[16];
    const float* bo  = (const float*)d_in[17];
    const float* al  = (const float*)d_in[18];
    float* out = (float*)d_out;

    // workspace: dh [8192*128] f32 (4 MB), then bf16 transposed weights
    float* dh = (float*)d_ws;
    unsigned short* w1bt = (unsigned short*)((char*)d_ws + (size_t)4194304);
    unsigned short* w2t = w1bt + 49152;    // w1bt: 128*384 shorts
    unsigned short* w3t = w2t + 16384;

    prep_w  <<<320,  256, 0, stream>>>(W1, W2, W3, w1bt, w2t, w3t);
    edge_mlp<<<4096, 256, 0, stream>>>(hV, hE, mA, W1, b1, w1bt, w2t, w3t, b2, b3, dh);
    node_ffn<<<512,  256, 0, stream>>>(hV, dh, mV, g1, be1, g2, be2, Wi, bi, Wo, bo, al, out);
}

// Round 4
// 932.617 us; speedup vs baseline: 1.0604x; 1.0065x over previous
//
#include <hip/hip_runtime.h>

#define LN_EPS 1e-5f
#define RSCALE (1.0f / 30.0f)

typedef short short8  __attribute__((ext_vector_type(8)));
typedef short short4v __attribute__((ext_vector_type(4)));
typedef float f32x4   __attribute__((ext_vector_type(4)));

__device__ __forceinline__ unsigned short f2bf(float f) {
    unsigned u = __builtin_bit_cast(unsigned, f);
    u = u + 0x7FFFu + ((u >> 16) & 1u);   // round-to-nearest-even
    return (unsigned short)(u >> 16);
}

__device__ __forceinline__ float bf2f(unsigned short h) {
    return __builtin_bit_cast(float, (unsigned)h << 16);
}

__device__ __forceinline__ float gelu_f(float x) {
    // tanh-form gelu; |err| vs exact erf-gelu ~3e-3, scaled by alpha=0.01 downstream
    float u  = 0.7978845608028654f * (x + 0.044715f * x * x * x);
    float e  = __expf(-2.0f * fabsf(u));
    float t  = 1.0f - 2.0f * e / (1.0f + e);
    return 0.5f * x * (1.0f + copysignf(t, u));
}

__device__ __forceinline__ f32x4 zero4() {
    f32x4 v; v.x = 0.f; v.y = 0.f; v.z = 0.f; v.w = 0.f; return v;
}

// ---------------------------------------------------------------------------
// Kernel 0: bf16-transpose weights.
//   w1bt: [128 m][384 k] = W1[128+k][m]   (h_E half of W1)
//   w2t/w3t: [128 m][128 k]
//   w1at: [128 m][128 k] = W1[k][m]       (h_V half of W1, for the prologue)
// ---------------------------------------------------------------------------
__global__ __launch_bounds__(256) void prep_w(
    const float* __restrict__ W1, const float* __restrict__ W2,
    const float* __restrict__ W3,
    unsigned short* __restrict__ w1bt, unsigned short* __restrict__ w2t,
    unsigned short* __restrict__ w3t, unsigned short* __restrict__ w1at)
{
    int t = blockIdx.x * 256 + threadIdx.x;
    if (t < 49152) {                       // W1 rows 128..511 -> w1bt [128][384]
        int m = t & 127, kk = t >> 7;
        w1bt[m * 384 + kk] = f2bf(W1[(kk + 128) * 128 + m]);
    } else if (t < 65536) {                // W2: [128][128] -> w2t [128][128]
        int u = t - 49152, m = u & 127, k = u >> 7;
        w2t[m * 128 + k] = f2bf(W2[k * 128 + m]);
    } else if (t < 81920) {                // W3
        int u = t - 65536, m = u & 127, k = u >> 7;
        w3t[m * 128 + k] = f2bf(W3[k * 128 + m]);
    } else if (t < 98304) {                // W1 rows 0..127 -> w1at [128][128]
        int u = t - 81920, m = u & 127, k = u >> 7;
        w1at[m * 128 + k] = f2bf(W1[k * 128 + m]);
    }
}

// ---------------------------------------------------------------------------
// Kernel 1: fused edge MLP + masked K-reduce -> dh
// 2 nodes/WG (96 edge rows), 4 waves. Wave w: node g=w&1, neuron half mh=w>>1.
// h_V@W1a+b1 is identical across the 48 neighbors of a node -> hoisted to a
// once-per-node prologue (fp32 hV x bf16 w1at, row-contiguous reads, LDS-
// broadcast hV) used as the MFMA accumulator init -> GEMM1 = 6 chunks of h_E.
// Single Hb buffer (in-place reuse) -> 52.4 KB LDS -> 3 wg/CU.
// h_E chunk register-double-buffered: pv loads issued right after the pre-MFMA
// barrier, consumed in the next iteration's staging phase (wave-private
// registers; barrier structure identical to the round-2 race-screened template).
// LDS XOR swizzle both sides: addr = row*ROWB + 16*(kb ^ (row&7)).
// ---------------------------------------------------------------------------
__global__ __launch_bounds__(256, 3) void edge_mlp(
    const float* __restrict__ hV, const float* __restrict__ hE,
    const float* __restrict__ mAtt,
    const float* __restrict__ b1,
    const unsigned short* __restrict__ w1bt, const unsigned short* __restrict__ w2t,
    const unsigned short* __restrict__ w3t, const unsigned short* __restrict__ w1at,
    const float* __restrict__ b2, const float* __restrict__ b3,
    float* __restrict__ dh)
{
    __shared__ __align__(16) short A1[96 * 64];    // edge-feature chunk [96][64]
    __shared__ __align__(16) short Wb[128 * 64];   // weight chunk [128][64]
    __shared__ __align__(16) short Hb[96 * 128];   // hidden activations (in-place reuse)
    __shared__ float mb[96];                       // mask_attend rows

    const int tid  = threadIdx.x;
    const int lane = tid & 63;
    const int wv   = tid >> 6;
    const int g    = wv & 1;
    const int mh   = wv >> 1;
    const int ln   = lane & 15;
    const int kg   = lane >> 4;
    const int node0 = blockIdx.x * 2;

    const int srow = tid >> 4;             // staging row 0..15
    const int c4   = (tid & 15) * 4;       // staging col (4 floats)
    const int kb_w = c4 >> 3;              // 16B sub-block 0..7
    const int c4lo = c4 & 4;               // 0|4 shorts within sub-block

    if (tid < 96) mb[tid] = mAtt[node0 * 48 + tid];

    // ---- issue h_E chunk-0 loads first (latency hidden under the prologue) ----
    float4 pv[6];
#pragma unroll
    for (int rep = 0; rep < 6; ++rep)
        pv[rep] = *(const float4*)(hE + (node0 * 48 + rep * 16 + srow) * 384 + c4);

    // ---- stage hV rows for both nodes into LDS (coalesced; broadcast reads) ----
    {
        float* hvs = (float*)A1 + 256;     // floats 256..511 of A1 region
        hvs[tid] = hV[(node0 + (tid >> 7)) * 128 + (tid & 127)];
    }
    __syncthreads();

    // ---- prologue: nodeV1[g][m] = b1[m] + sum_k hV[n][k] * W1a[k][m] ----
    float* nv = (float*)A1;                // floats 0..255 of A1 region
    {
        const int gg = tid >> 7, m = tid & 127;
        const float* hv = (const float*)A1 + 256 + gg * 128;  // LDS broadcast
        const unsigned short* wa = w1at + m * 128;            // row-contiguous
        float a0 = 0.f, a1 = 0.f, a2 = 0.f, a3 = 0.f;
        for (int k = 0; k < 128; k += 8) {
            short8 w8 = *(const short8*)(wa + k);
            a0 += hv[k + 0] * bf2f((unsigned short)w8[0]);
            a1 += hv[k + 1] * bf2f((unsigned short)w8[1]);
            a2 += hv[k + 2] * bf2f((unsigned short)w8[2]);
            a3 += hv[k + 3] * bf2f((unsigned short)w8[3]);
            a0 += hv[k + 4] * bf2f((unsigned short)w8[4]);
            a1 += hv[k + 5] * bf2f((unsigned short)w8[5]);
            a2 += hv[k + 6] * bf2f((unsigned short)w8[6]);
            a3 += hv[k + 7] * bf2f((unsigned short)w8[7]);
        }
        const float r = b1[m] + (a0 + a1) + (a2 + a3);
        __syncthreads();                   // all hvs reads done before nv write
        nv[tid] = r;
    }
    __syncthreads();

    // ---- acc init from nodeV1 (same value for every edge row of the node) ----
    f32x4 acc[4][3];
#pragma unroll
    for (int j = 0; j < 4; ++j) {
        const float4 iv = *(const float4*)&nv[g * 128 + (4 * mh + j) * 16 + kg * 4];
#pragma unroll
        for (int i = 0; i < 3; ++i) {
            acc[j][i].x = iv.x; acc[j][i].y = iv.y;
            acc[j][i].z = iv.z; acc[j][i].w = iv.w;
        }
    }
    __syncthreads();                       // nv reads done; A1 free for staging

    // -------- GEMM1: hE[96x384] @ W1b, 6 K-chunks of 64, reg-dbuf on A --------
    for (int c = 0; c < 6; ++c) {
        const int kc = c * 64;
        // stage A chunk from prefetched registers (fp32 -> bf16)
#pragma unroll
        for (int rep = 0; rep < 6; ++rep) {
            const int r = rep * 16 + srow;
            short4v p;
            p.x = (short)f2bf(pv[rep].x); p.y = (short)f2bf(pv[rep].y);
            p.z = (short)f2bf(pv[rep].z); p.w = (short)f2bf(pv[rep].w);
            *(short4v*)&A1[r * 64 + ((kb_w ^ (r & 7)) * 8) + c4lo] = p;
        }
        // stage W1T chunk (already bf16)
#pragma unroll
        for (int rep = 0; rep < 4; ++rep) {
            const int u = rep * 256 + tid;
            const int m = u >> 3, kb = u & 7;
            short8 val = *(const short8*)(w1bt + m * 384 + kc + kb * 8);
            *(short8*)&Wb[m * 64 + ((kb ^ (m & 7)) * 8)] = val;
        }
        __syncthreads();
        // prefetch next h_E chunk NOW: HBM latency overlaps the MFMA phase
        if (c < 5) {
#pragma unroll
            for (int rep = 0; rep < 6; ++rep) {
                const int r = rep * 16 + srow;
                pv[rep] = *(const float4*)(hE + (node0 * 48 + r) * 384 + (kc + 64) + c4);
            }
        }
#pragma unroll
        for (int s = 0; s < 2; ++s) {
            const int kb = s * 4 + kg;
            short8 bf[3], af[4];
#pragma unroll
            for (int i = 0; i < 3; ++i) {
                const int r = (3 * g + i) * 16 + ln;
                bf[i] = *(const short8*)&A1[r * 64 + ((kb ^ (r & 7)) * 8)];
            }
#pragma unroll
            for (int j = 0; j < 4; ++j) {
                const int m = (4 * mh + j) * 16 + ln;
                af[j] = *(const short8*)&Wb[m * 64 + ((kb ^ (m & 7)) * 8)];
            }
#pragma unroll
            for (int j = 0; j < 4; ++j)
#pragma unroll
                for (int i = 0; i < 3; ++i)
                    acc[j][i] = __builtin_amdgcn_mfma_f32_16x16x32_bf16(af[j], bf[i], acc[j][i], 0, 0, 0);
        }
        __syncthreads();
    }

    // epilogue 1: gelu(x) -> Hb   (b1 already folded into nodeV1 init)
#pragma unroll
    for (int j = 0; j < 4; ++j) {
        const int m0 = (4 * mh + j) * 16 + kg * 4;
#pragma unroll
        for (int i = 0; i < 3; ++i) {
            const int r = (3 * g + i) * 16 + ln;
            short4v p;
            p.x = (short)f2bf(gelu_f(acc[j][i].x));
            p.y = (short)f2bf(gelu_f(acc[j][i].y));
            p.z = (short)f2bf(gelu_f(acc[j][i].z));
            p.w = (short)f2bf(gelu_f(acc[j][i].w));
            *(short4v*)&Hb[r * 128 + (((m0 >> 3) ^ (r & 7)) * 8) + (m0 & 4)] = p;
        }
    }

    // -------- GEMM2 (Hb @ W2 -> Hb, in place) and GEMM3 (Hb @ W3 -> reduce) ----
    for (int L = 0; L < 2; ++L) {
#pragma unroll
        for (int j = 0; j < 4; ++j)
#pragma unroll
            for (int i = 0; i < 3; ++i) acc[j][i] = zero4();

        const unsigned short* wt = (L == 0) ? w2t : w3t;
        for (int c = 0; c < 2; ++c) {
            const int kc = c * 64;
#pragma unroll
            for (int rep = 0; rep < 4; ++rep) {
                const int u = rep * 256 + tid;
                const int m = u >> 3, kb = u & 7;
                short8 val = *(const short8*)(wt + m * 128 + kc + kb * 8);
                *(short8*)&Wb[m * 64 + ((kb ^ (m & 7)) * 8)] = val;
            }
            __syncthreads();
#pragma unroll
            for (int s = 0; s < 2; ++s) {
                const int kbW = s * 4 + kg;
                const int kbH = c * 8 + s * 4 + kg;
                short8 bf[3], af[4];
#pragma unroll
                for (int i = 0; i < 3; ++i) {
                    const int r = (3 * g + i) * 16 + ln;
                    bf[i] = *(const short8*)&Hb[r * 128 + ((kbH ^ (r & 7)) * 8)];
                }
#pragma unroll
                for (int j = 0; j < 4; ++j) {
                    const int m = (4 * mh + j) * 16 + ln;
                    af[j] = *(const short8*)&Wb[m * 64 + ((kbW ^ (m & 7)) * 8)];
                }
#pragma unroll
                for (int j = 0; j < 4; ++j)
#pragma unroll
                    for (int i = 0; i < 3; ++i)
                        acc[j][i] = __builtin_amdgcn_mfma_f32_16x16x32_bf16(af[j], bf[i], acc[j][i], 0, 0, 0);
            }
            __syncthreads();
        }

        if (L == 0) {
            // epilogue 2: gelu(x + b2) -> Hb (all reads of old Hb completed above)
#pragma unroll
            for (int j = 0; j < 4; ++j) {
                const int m0 = (4 * mh + j) * 16 + kg * 4;
                const float4 bb = *(const float4*)(b2 + m0);
#pragma unroll
                for (int i = 0; i < 3; ++i) {
                    const int r = (3 * g + i) * 16 + ln;
                    short4v p;
                    p.x = (short)f2bf(gelu_f(acc[j][i].x + bb.x));
                    p.y = (short)f2bf(gelu_f(acc[j][i].y + bb.y));
                    p.z = (short)f2bf(gelu_f(acc[j][i].z + bb.z));
                    p.w = (short)f2bf(gelu_f(acc[j][i].w + bb.w));
                    *(short4v*)&Hb[r * 128 + (((m0 >> 3) ^ (r & 7)) * 8) + (m0 & 4)] = p;
                }
            }
        } else {
            // epilogue 3: dh[node][m] = (1/30) * sum_rows mask*(x + b3)
#pragma unroll
            for (int j = 0; j < 4; ++j) {
                const int m0 = (4 * mh + j) * 16 + kg * 4;
                const float4 bb = *(const float4*)(b3 + m0);
                float s0 = 0.f, s1 = 0.f, s2 = 0.f, s3 = 0.f;
#pragma unroll
                for (int i = 0; i < 3; ++i) {
                    const int r = (3 * g + i) * 16 + ln;
                    const float mk = mb[r];
                    s0 += (acc[j][i].x + bb.x) * mk;
                    s1 += (acc[j][i].y + bb.y) * mk;
                    s2 += (acc[j][i].z + bb.z) * mk;
                    s3 += (acc[j][i].w + bb.w) * mk;
                }
#pragma unroll
                for (int off = 1; off < 16; off <<= 1) {
                    s0 += __shfl_xor(s0, off, 64);
                    s1 += __shfl_xor(s1, off, 64);
                    s2 += __shfl_xor(s2, off, 64);
                    s3 += __shfl_xor(s3, off, 64);
                }
                if (ln == 0) {
                    float4 o;
                    o.x = s0 * RSCALE; o.y = s1 * RSCALE;
                    o.z = s2 * RSCALE; o.w = s3 * RSCALE;
                    *(float4*)&dh[(node0 + g) * 128 + m0] = o;
                }
            }
        }
    }
}

// ---------------------------------------------------------------------------
// Kernel 2: per-node rezero+LN1 -> FFN(128->512->128) -> rezero+LN2 -> mask
// 16 nodes per WG, 512 WGs, fp32 VALU.
// ---------------------------------------------------------------------------
__global__ __launch_bounds__(256, 2) void node_ffn(
    const float* __restrict__ hV, const float* __restrict__ dh,
    const float* __restrict__ maskV,
    const float* __restrict__ g1, const float* __restrict__ be1,
    const float* __restrict__ g2, const float* __restrict__ be2,
    const float* __restrict__ Wi, const float* __restrict__ bi,
    const float* __restrict__ Wo, const float* __restrict__ bo,
    const float* __restrict__ alphap, float* __restrict__ out)
{
    __shared__ float hbuf[16 * 132];   // post-LN1 h
    __shared__ float hidb[16 * 516];   // hidden (512) per node
    __shared__ float obuf[16 * 132];   // FFN output

    const int tid = threadIdx.x;
    const float al = alphap[0];
    const int nb = blockIdx.x * 16;

    // ---- phase 1: x = hV + al*dh; LN1 -> hbuf ----
    {
        const int m = tid >> 4, s = tid & 15;
        const int i0 = s * 8;
        const int base = (nb + m) * 128 + i0;
        float x[8];
        {
            float4 a0 = *(const float4*)(dh + base);
            float4 a1 = *(const float4*)(dh + base + 4);
            float4 v0 = *(const float4*)(hV + base);
            float4 v1 = *(const float4*)(hV + base + 4);
            x[0] = v0.x + al * a0.x; x[1] = v0.y + al * a0.y;
            x[2] = v0.z + al * a0.z; x[3] = v0.w + al * a0.w;
            x[4] = v1.x + al * a1.x; x[5] = v1.y + al * a1.y;
            x[6] = v1.z + al * a1.z; x[7] = v1.w + al * a1.w;
        }
        float sm = 0.f;
#pragma unroll
        for (int q = 0; q < 8; ++q) sm += x[q];
#pragma unroll
        for (int off = 1; off < 16; off <<= 1) sm += __shfl_xor(sm, off, 64);
        const float mu = sm * (1.0f / 128.0f);
        float vs = 0.f;
#pragma unroll
        for (int q = 0; q < 8; ++q) { float d = x[q] - mu; vs += d * d; }
#pragma unroll
        for (int off = 1; off < 16; off <<= 1) vs += __shfl_xor(vs, off, 64);
        const float rs = rsqrtf(vs * (1.0f / 128.0f) + LN_EPS);
#pragma unroll
        for (int q = 0; q < 8; ++q)
            hbuf[m * 132 + i0 + q] = (x[q] - mu) * rs * g1[i0 + q] + be1[i0 + q];
    }
    __syncthreads();

    // ---- phase 2: hid = gelu(h @ Wi + bi) ----
    {
        const int jg = tid & 127, mhh = tid >> 7;
        const int j4 = jg * 4;
        float acc[8][4];
#pragma unroll
        for (int mm = 0; mm < 8; ++mm)
#pragma unroll
            for (int jj = 0; jj < 4; ++jj) acc[mm][jj] = 0.f;
        for (int i0 = 0; i0 < 128; i0 += 4) {
            float4 w0 = *(const float4*)(Wi + (i0 + 0) * 512 + j4);
            float4 w1 = *(const float4*)(Wi + (i0 + 1) * 512 + j4);
            float4 w2 = *(const float4*)(Wi + (i0 + 2) * 512 + j4);
            float4 w3 = *(const float4*)(Wi + (i0 + 3) * 512 + j4);
#pragma unroll
            for (int mm = 0; mm < 8; ++mm) {
                float4 h4 = *(const float4*)&hbuf[(mhh * 8 + mm) * 132 + i0];
                acc[mm][0] += h4.x * w0.x + h4.y * w1.x + h4.z * w2.x + h4.w * w3.x;
                acc[mm][1] += h4.x * w0.y + h4.y * w1.y + h4.z * w2.y + h4.w * w3.y;
                acc[mm][2] += h4.x * w0.z + h4.y * w1.z + h4.z * w2.z + h4.w * w3.z;
                acc[mm][3] += h4.x * w0.w + h4.y * w1.w + h4.z * w2.w + h4.w * w3.w;
            }
        }
        float4 bb = *(const float4*)(bi + j4);
#pragma unroll
        for (int mm = 0; mm < 8; ++mm) {
            float4 o;
            o.x = gelu_f(acc[mm][0] + bb.x);
            o.y = gelu_f(acc[mm][1] + bb.y);
            o.z = gelu_f(acc[mm][2] + bb.z);
            o.w = gelu_f(acc[mm][3] + bb.w);
            *(float4*)&hidb[(mhh * 8 + mm) * 516 + j4] = o;
        }
    }
    __syncthreads();

    // ---- phase 3: o = hid @ Wo + bo -> obuf ----
    {
        const int m = tid >> 4;
        const int n8 = (tid & 15) * 8;
        float4 r0, r1;
        r0.x = r0.y = r0.z = r0.w = 0.f;
        r1.x = r1.y = r1.z = r1.w = 0.f;
        for (int j0 = 0; j0 < 512; j0 += 4) {
            float4 hh = *(const float4*)&hidb[m * 516 + j0];
            float hq[4] = {hh.x, hh.y, hh.z, hh.w};
#pragma unroll
            for (int jj = 0; jj < 4; ++jj) {
                float4 w0 = *(const float4*)(Wo + (j0 + jj) * 128 + n8);
                float4 w1 = *(const float4*)(Wo + (j0 + jj) * 128 + n8 + 4);
                r0.x += hq[jj] * w0.x; r0.y += hq[jj] * w0.y;
                r0.z += hq[jj] * w0.z; r0.w += hq[jj] * w0.w;
                r1.x += hq[jj] * w1.x; r1.y += hq[jj] * w1.y;
                r1.z += hq[jj] * w1.z; r1.w += hq[jj] * w1.w;
            }
        }
        float4 q0 = *(const float4*)(bo + n8);
        float4 q1 = *(const float4*)(bo + n8 + 4);
        r0.x += q0.x; r0.y += q0.y; r0.z += q0.z; r0.w += q0.w;
        r1.x += q1.x; r1.y += q1.y; r1.z += q1.z; r1.w += q1.w;
        *(float4*)&obuf[m * 132 + n8]     = r0;
        *(float4*)&obuf[m * 132 + n8 + 4] = r1;
    }
    __syncthreads();

    // ---- phase 4: x = h + al*o; LN2; mask; store ----
    {
        const int m = tid >> 4, s = tid & 15;
        const int i0 = s * 8;
        float x[8];
#pragma unroll
        for (int q = 0; q < 8; ++q)
            x[q] = hbuf[m * 132 + i0 + q] + al * obuf[m * 132 + i0 + q];
        float sm = 0.f;
#pragma unroll
        for (int q = 0; q < 8; ++q) sm += x[q];
#pragma unroll
        for (int off = 1; off < 16; off <<= 1) sm += __shfl_xor(sm, off, 64);
        const float mu = sm * (1.0f / 128.0f);
        float vs = 0.f;
#pragma unroll
        for (int q = 0; q < 8; ++q) { float d = x[q] - mu; vs += d * d; }
#pragma unroll
        for (int off = 1; off < 16; off <<= 1) vs += __shfl_xor(vs, off, 64);
        const float rs = rsqrtf(vs * (1.0f / 128.0f) + LN_EPS);
        const float mk = maskV[nb + m];
        float y[8];
#pragma unroll
        for (int q = 0; q < 8; ++q)
            y[q] = ((x[q] - mu) * rs * g2[i0 + q] + be2[i0 + q]) * mk;
        float4 o0, o1;
        o0.x = y[0]; o0.y = y[1]; o0.z = y[2]; o0.w = y[3];
        o1.x = y[4]; o1.y = y[5]; o1.z = y[6]; o1.w = y[7];
        const int base = (nb + m) * 128 + i0;
        *(float4*)(out + base)     = o0;
        *(float4*)(out + base + 4) = o1;
    }
}

// ---------------------------------------------------------------------------
extern "C" void kernel_launch(void* const* d_in, const int* in_sizes, int n_in,
                              void* d_out, int out_size, void* d_ws, size_t ws_size,
                              hipStream_t stream)
{
    const float* hV  = (const float*)d_in[0];
    const float* hE  = (const float*)d_in[1];
    const float* mV  = (const float*)d_in[2];
    const float* mA  = (const float*)d_in[3];
    const float* W1  = (const float*)d_in[4];
    const float* b1  = (const float*)d_in[5];
    const float* W2  = (const float*)d_in[6];
    const float* b2  = (const float*)d_in[7];
    const float* W3  = (const float*)d_in[8];
    const float* b3  = (const float*)d_in[9];
    const float* g1  = (const float*)d_in[10];
    const float* be1 = (const float*)d_in[11];
    const float* g2  = (const float*)d_in[12];
    const float* be2 = (const float*)d_in[13];
    const float* Wi  = (const float*)d_in[14];
    const float* bi  = (const float*)d_in[15];
    const float* Wo  = (const float*)d_in[16];
    const float* bo  = (const float*)d_in[17];
    const float* al  = (const float*)d_in[18];
    float* out = (float*)d_out;

    // workspace: dh [8192*128] f32 (4 MB), then bf16 transposed weights
    float* dh = (float*)d_ws;
    unsigned short* w1bt = (unsigned short*)((char*)d_ws + (size_t)4194304);
    unsigned short* w2t  = w1bt + 49152;   // w1bt: 128*384 shorts
    unsigned short* w3t  = w2t + 16384;
    unsigned short* w1at = w3t + 16384;    // 128*128 shorts

    prep_w  <<<384,  256, 0, stream>>>(W1, W2, W3, w1bt, w2t, w3t, w1at);
    edge_mlp<<<4096, 256, 0, stream>>>(hV, hE, mA, b1, w1bt, w2t, w3t, w1at, b2, b3, dh);
    node_ffn<<<512,  256, 0, stream>>>(hV, dh, mV, g1, be1, g2, be2, Wi, bi, Wo, bo, al, out);
}